// Round 1
// baseline (1897.474 us; speedup 1.0000x reference)
//
#include <hip/hip_runtime.h>

#define CAP   262144
#define CAPM  (CAP - 1)
#define DM    1024
#define NTOK  131072

// inv[p] = -1 everywhere (d_ws is poisoned 0xAA before every timed launch)
__global__ void k_init_inv(int* __restrict__ inv) {
    int g = blockIdx.x * 256 + threadIdx.x;
    if (g < CAP) inv[g] = -1;
}

// per-block mask sums (block = 256 threads, 1 elem/thread)
__global__ void k_block_sums(const int* __restrict__ vis, const int* __restrict__ vld,
                             int* __restrict__ bsum) {
    int i = blockIdx.x * 256 + threadIdx.x;
    int m = (vis[i] != 0 && vld[i] != 0) ? 1 : 0;
    for (int off = 32; off > 0; off >>= 1) m += __shfl_down(m, off, 64);
    __shared__ int ws4[4];
    int lane = threadIdx.x & 63, wid = threadIdx.x >> 6;
    if (lane == 0) ws4[wid] = m;
    __syncthreads();
    if (threadIdx.x == 0) bsum[blockIdx.x] = ws4[0] + ws4[1] + ws4[2] + ws4[3];
}

// single-block exclusive scan of the 512 block sums; also emit new_ptr output
__global__ void k_scan_bsums(const int* __restrict__ bsum, int* __restrict__ boffs,
                             const int* __restrict__ wptr, float* __restrict__ newptr_out) {
    __shared__ int s[512];
    int t = threadIdx.x;
    int v = bsum[t];
    s[t] = v;
    __syncthreads();
    for (int off = 1; off < 512; off <<= 1) {
        int x = (t >= off) ? s[t - off] : 0;
        __syncthreads();
        s[t] += x;
        __syncthreads();
    }
    boffs[t] = s[t] - v;  // exclusive prefix
    if (t == 511) {
        int total = s[511];
        *newptr_out = (float)((wptr[0] + total) & CAPM);
    }
}

// recompute mask, block-local exclusive scan, scatter inverse index
__global__ void k_scatter(const int* __restrict__ vis, const int* __restrict__ vld,
                          const int* __restrict__ boffs, const int* __restrict__ wptr,
                          int* __restrict__ inv) {
    int t = threadIdx.x;
    int i = blockIdx.x * 256 + t;
    int m = (vis[i] != 0 && vld[i] != 0) ? 1 : 0;
    __shared__ int s[256];
    s[t] = m;
    __syncthreads();
    for (int off = 1; off < 256; off <<= 1) {
        int x = (t >= off) ? s[t - off] : 0;
        __syncthreads();
        s[t] += x;
        __syncthreads();
    }
    if (m) {
        int rank = boffs[blockIdx.x] + (s[t] - m);
        int pos  = (wptr[0] + rank) & CAPM;
        inv[pos] = i;
    }
}

// one 4KiB row per block-iteration: gather from tokens (if scattered) or memtok
#define ROWS_PER_BLOCK 4
__global__ void k_gather(const float* __restrict__ tokens, const float* __restrict__ memtok,
                         const int* __restrict__ oslot,
                         const int* __restrict__ oid_in, const int* __restrict__ fid_in,
                         const int* __restrict__ vbuf_in, const int* __restrict__ frame_id,
                         const int* __restrict__ inv, float* __restrict__ out) {
    float* oid_out = out + (size_t)CAP * DM;
    float* fid_out = oid_out + CAP;
    float* val_out = fid_out + CAP;
    for (int r = 0; r < ROWS_PER_BLOCK; ++r) {
        int p = blockIdx.x * ROWS_PER_BLOCK + r;   // uniform per block -> scalar loads
        int t = inv[p];
        const float4* src = (const float4*)((t >= 0) ? tokens + (size_t)t * DM
                                                     : memtok + (size_t)p * DM);
        float4* dst = (float4*)(out + (size_t)p * DM);
        dst[threadIdx.x] = src[threadIdx.x];       // 256 threads x 16B = 4KiB row
        if (threadIdx.x == 0) {
            if (t >= 0) {
                oid_out[p] = (float)oslot[t];
                fid_out[p] = (float)frame_id[0];
                val_out[p] = 1.0f;
            } else {
                oid_out[p] = (float)oid_in[p];
                fid_out[p] = (float)fid_in[p];
                val_out[p] = (vbuf_in[p] != 0) ? 1.0f : 0.0f;
            }
        }
    }
}

extern "C" void kernel_launch(void* const* d_in, const int* in_sizes, int n_in,
                              void* d_out, int out_size, void* d_ws, size_t ws_size,
                              hipStream_t stream) {
    const float* tokens   = (const float*)d_in[0];   // (N, D) f32
    const float* memtok   = (const float*)d_in[1];   // (CAP, D) f32
    const int*   oslot    = (const int*)d_in[2];     // (N,) i32
    const int*   vis      = (const int*)d_in[3];     // (N,) bool->i32
    const int*   vld      = (const int*)d_in[4];     // (N,) bool->i32
    const int*   oid_in   = (const int*)d_in[5];     // (CAP,) i32
    const int*   fid_in   = (const int*)d_in[6];     // (CAP,) i32
    const int*   vbuf     = (const int*)d_in[7];     // (CAP,) bool->i32
    const int*   frame_id = (const int*)d_in[8];     // scalar i32
    const int*   wptr     = (const int*)d_in[9];     // scalar i32
    float* out = (float*)d_out;

    int* inv   = (int*)d_ws;          // CAP ints
    int* bsum  = inv + CAP;           // 512 ints
    int* boffs = bsum + 512;          // 512 ints
    float* newptr_out = out + (size_t)CAP * DM + 3 * (size_t)CAP;  // last output elem

    k_init_inv  <<<CAP / 256, 256, 0, stream>>>(inv);
    k_block_sums<<<NTOK / 256, 256, 0, stream>>>(vis, vld, bsum);
    k_scan_bsums<<<1, 512, 0, stream>>>(bsum, boffs, wptr, newptr_out);
    k_scatter   <<<NTOK / 256, 256, 0, stream>>>(vis, vld, boffs, wptr, inv);
    k_gather    <<<CAP / ROWS_PER_BLOCK, 256, 0, stream>>>(tokens, memtok, oslot,
                                                           oid_in, fid_in, vbuf,
                                                           frame_id, inv, out);
}

// Round 2
// 1875.433 us; speedup vs baseline: 1.0118x; 1.0118x over previous
//
#include <hip/hip_runtime.h>

#define CAP    262144
#define CAPM   (CAP - 1)
#define DM     1024
#define NTOK   131072
#define ROW_F4 (DM / 4)   // 256 float4 per row

// Fused: inv[p] = -1 over CAP  +  per-256-block mask sums over NTOK.
// grid = CAP/256 = 1024 blocks; first NTOK/256 = 512 blocks also do sums.
__global__ void k_init_and_sums(const int* __restrict__ vis, const int* __restrict__ vld,
                                int* __restrict__ inv, int* __restrict__ bsum) {
    int g = blockIdx.x * 256 + threadIdx.x;
    inv[g] = -1;
    if (g < NTOK) {
        int m = (vis[g] != 0 && vld[g] != 0) ? 1 : 0;
        for (int off = 32; off > 0; off >>= 1) m += __shfl_down(m, off, 64);
        __shared__ int ws4[4];
        int lane = threadIdx.x & 63, wid = threadIdx.x >> 6;
        if (lane == 0) ws4[wid] = m;
        __syncthreads();
        if (threadIdx.x == 0) bsum[blockIdx.x] = ws4[0] + ws4[1] + ws4[2] + ws4[3];
    }
}

// single-block exclusive scan of the 512 block sums; also emit new_ptr output
__global__ void k_scan_bsums(const int* __restrict__ bsum, int* __restrict__ boffs,
                             const int* __restrict__ wptr, float* __restrict__ newptr_out) {
    __shared__ int s[512];
    int t = threadIdx.x;
    int v = bsum[t];
    s[t] = v;
    __syncthreads();
    for (int off = 1; off < 512; off <<= 1) {
        int x = (t >= off) ? s[t - off] : 0;
        __syncthreads();
        s[t] += x;
        __syncthreads();
    }
    boffs[t] = s[t] - v;  // exclusive prefix
    if (t == 511) {
        int total = s[511];
        *newptr_out = (float)((wptr[0] + total) & CAPM);
    }
}

// recompute mask, block-local exclusive scan, scatter inverse index
__global__ void k_scatter(const int* __restrict__ vis, const int* __restrict__ vld,
                          const int* __restrict__ boffs, const int* __restrict__ wptr,
                          int* __restrict__ inv) {
    int t = threadIdx.x;
    int i = blockIdx.x * 256 + t;
    int m = (vis[i] != 0 && vld[i] != 0) ? 1 : 0;
    __shared__ int s[256];
    s[t] = m;
    __syncthreads();
    for (int off = 1; off < 256; off <<= 1) {
        int x = (t >= off) ? s[t - off] : 0;
        __syncthreads();
        s[t] += x;
        __syncthreads();
    }
    if (m) {
        int rank = boffs[blockIdx.x] + (s[t] - m);
        int pos  = (wptr[0] + rank) & CAPM;
        inv[pos] = i;
    }
}

// metadata outputs, fully coalesced: one thread per slot p
__global__ void k_meta(const int* __restrict__ inv, const int* __restrict__ oslot,
                       const int* __restrict__ oid_in, const int* __restrict__ fid_in,
                       const int* __restrict__ vbuf, const int* __restrict__ frame_id,
                       float* __restrict__ out) {
    int p = blockIdx.x * 256 + threadIdx.x;
    float* oid_out = out + (size_t)CAP * DM;
    float* fid_out = oid_out + CAP;
    float* val_out = fid_out + CAP;
    int t = inv[p];
    if (t >= 0) {
        oid_out[p] = (float)oslot[t];
        fid_out[p] = (float)frame_id[0];
        val_out[p] = 1.0f;
    } else {
        oid_out[p] = (float)oid_in[p];
        fid_out[p] = (float)fid_in[p];
        val_out[p] = (vbuf[p] != 0) ? 1.0f : 0.0f;
    }
}

// one 4 KiB row per block: 256 threads x float4. inv[p] is a broadcast load.
__global__ void k_copy(const float4* __restrict__ tokens, const float4* __restrict__ memtok,
                       const int* __restrict__ inv, float4* __restrict__ out) {
    int p = blockIdx.x;
    int t = inv[p];
    const float4* src = (t >= 0) ? tokens + (size_t)t * ROW_F4
                                 : memtok + (size_t)p * ROW_F4;
    out[(size_t)p * ROW_F4 + threadIdx.x] = src[threadIdx.x];
}

extern "C" void kernel_launch(void* const* d_in, const int* in_sizes, int n_in,
                              void* d_out, int out_size, void* d_ws, size_t ws_size,
                              hipStream_t stream) {
    const float* tokens   = (const float*)d_in[0];   // (N, D) f32
    const float* memtok   = (const float*)d_in[1];   // (CAP, D) f32
    const int*   oslot    = (const int*)d_in[2];     // (N,) i32
    const int*   vis      = (const int*)d_in[3];     // (N,) bool->i32
    const int*   vld      = (const int*)d_in[4];     // (N,) bool->i32
    const int*   oid_in   = (const int*)d_in[5];     // (CAP,) i32
    const int*   fid_in   = (const int*)d_in[6];     // (CAP,) i32
    const int*   vbuf     = (const int*)d_in[7];     // (CAP,) bool->i32
    const int*   frame_id = (const int*)d_in[8];     // scalar i32
    const int*   wptr     = (const int*)d_in[9];     // scalar i32
    float* out = (float*)d_out;

    int* inv   = (int*)d_ws;          // CAP ints
    int* bsum  = inv + CAP;           // 512 ints
    int* boffs = bsum + 512;          // 512 ints
    float* newptr_out = out + (size_t)CAP * DM + 3 * (size_t)CAP;  // last output elem

    k_init_and_sums<<<CAP / 256, 256, 0, stream>>>(vis, vld, inv, bsum);
    k_scan_bsums   <<<1, 512, 0, stream>>>(bsum, boffs, wptr, newptr_out);
    k_scatter      <<<NTOK / 256, 256, 0, stream>>>(vis, vld, boffs, wptr, inv);
    k_meta         <<<CAP / 256, 256, 0, stream>>>(inv, oslot, oid_in, fid_in, vbuf,
                                                   frame_id, out);
    k_copy         <<<CAP, 256, 0, stream>>>((const float4*)tokens, (const float4*)memtok,
                                             inv, (float4*)out);
}